// Round 11
// baseline (127.402 us; speedup 1.0000x reference)
//
#include <hip/hip_runtime.h>
#include <hip/hip_bf16.h>

#define D_MODEL 1024
#define HEADS 16
#define HDIM 64
#define BATCH 2
#define SEQ 2048
#define MROWS (BATCH*SEQ)   // 4096

typedef __attribute__((ext_vector_type(8))) short bf16x8;
typedef __attribute__((ext_vector_type(4))) float f32x4;
typedef __attribute__((ext_vector_type(16))) float f32x16;
typedef __attribute__((ext_vector_type(4))) float float4v;
typedef __attribute__((ext_vector_type(4))) unsigned u32x4;
typedef __attribute__((ext_vector_type(4))) short s16x4;

typedef const __attribute__((address_space(1))) void gconst_t;
typedef __attribute__((address_space(3))) void lds_t;
#define GLD16(g, l) __builtin_amdgcn_global_load_lds((gconst_t*)(g), (lds_t*)(l), 16, 0, 0)

#if __has_builtin(__builtin_amdgcn_exp2f)
#define EXP2(x) __builtin_amdgcn_exp2f(x)   // raw v_exp_f32, intrinsic (not asm)
#else
#define EXP2(x) __builtin_exp2f(x)
#endif

__device__ __forceinline__ unsigned short f2b(float f) {
  unsigned u = __builtin_bit_cast(unsigned, f);
  u += 0x7fffu + ((u >> 16) & 1u);
  return (unsigned short)(u >> 16);
}

__device__ __forceinline__ unsigned cvtpk(float lo, float hi) {
  unsigned r;
  asm volatile("v_cvt_pk_bf16_f32 %0, %1, %2" : "=v"(r) : "v"(lo), "v"(hi));
  return r;
}

__global__ __launch_bounds__(256)
void cast_all(const float* __restrict__ Q, const float* __restrict__ K,
              const float* __restrict__ V, const float* __restrict__ Wq,
              const float* __restrict__ Wk, const float* __restrict__ Wv,
              const float* __restrict__ Wo, char* __restrict__ ws)
{
  const size_t MB = 1024*1024;
  int b = blockIdx.x;
  const float* src; short* dst; int rb;
  if (b < 6144) {
    int t = b >> 11; rb = b & 2047;
    src = (t == 0) ? Q : (t == 1) ? K : V;
    dst = (short*)(ws + (size_t)t*8*MB);
  } else {
    int t = (b - 6144) >> 9; rb = (b - 6144) & 511;
    src = (t == 0) ? Wq : (t == 1) ? Wk : (t == 2) ? Wv : Wo;
    dst = (short*)(ws + (24 + 2*(size_t)t)*MB);
  }
  int i = rb*256 + threadIdx.x;
  const float4v* s = (const float4v*)src;
  float4v a = s[2*(size_t)i], c = s[2*(size_t)i + 1];
  bf16x8 o;
  o[0] = (short)f2b(a[0]); o[1] = (short)f2b(a[1]);
  o[2] = (short)f2b(a[2]); o[3] = (short)f2b(a[3]);
  o[4] = (short)f2b(c[0]); o[5] = (short)f2b(c[1]);
  o[6] = (short)f2b(c[2]); o[7] = (short)f2b(c[3]);
  *(bf16x8*)(dst + 8*(size_t)i) = o;
}

// ---- merged Q/K/V projection GEMM, BK=64, XOR-swizzled, DOUBLE-BUFFERED ----
// (round-9 known-good) z=0: Q -> qp scaled by 0.125*log2e; z=1: K; z=2: V^T.
__global__ __launch_bounds__(256)
void gemm_qkv(const short* __restrict__ Qb, const short* __restrict__ Kb,
              const short* __restrict__ Vb, const short* __restrict__ Wqb,
              const short* __restrict__ Wkb, const short* __restrict__ Wvb,
              const float* __restrict__ bq, const float* __restrict__ bk,
              const float* __restrict__ bv, short* __restrict__ qp,
              short* __restrict__ kp, short* __restrict__ vp)
{
  __shared__ __align__(16) char smemc[65536];
  short* const lA0 = (short*)smemc;                 // buf0 A (16 KB)
  short* const lA1 = (short*)(smemc + 16384);       // buf1 A
  short* const lB0 = (short*)(smemc + 32768);       // buf0 B
  short* const lB1 = (short*)(smemc + 49152);       // buf1 B
  short* const lT  = (short*)smemc;                 // epilogue reuse (33 KB)

  const int z = blockIdx.z;
  const short* A = (z == 0) ? Qb : (z == 1) ? Kb : Vb;
  const short* W = (z == 0) ? Wqb : (z == 1) ? Wkb : Wvb;
  const float* bias = (z == 0) ? bq : (z == 1) ? bk : bv;

  const int tid  = threadIdx.x;
  const int wid  = tid >> 6;
  const int lane = tid & 63;
  const int bm = blockIdx.x, bn = blockIdx.y;
  const int wr = wid >> 1, wc = wid & 1;

  f32x4 acc[4][4] = {};

  const int srow = tid >> 3;
  const int cswz = (((tid & 7) * 16) ^ ((srow & 7) << 4)) >> 1;
  const short* gA = A + (size_t)(bm*128 + srow)*D_MODEL + cswz;
  const short* gB = W + (size_t)(bn*128 + srow)*D_MODEL + cswz;

#define QKV_STAGE(kt, bA, bB) do { \
    const int ko_ = (kt)*64; \
    GLD16(gA + ko_,              (bA) + (     wid*8)*64); \
    GLD16(gA + 32*D_MODEL + ko_, (bA) + (32 + wid*8)*64); \
    GLD16(gA + 64*D_MODEL + ko_, (bA) + (64 + wid*8)*64); \
    GLD16(gA + 96*D_MODEL + ko_, (bA) + (96 + wid*8)*64); \
    GLD16(gB + ko_,              (bB) + (     wid*8)*64); \
    GLD16(gB + 32*D_MODEL + ko_, (bB) + (32 + wid*8)*64); \
    GLD16(gB + 64*D_MODEL + ko_, (bB) + (64 + wid*8)*64); \
    GLD16(gB + 96*D_MODEL + ko_, (bB) + (96 + wid*8)*64); \
  } while (0)

  const int fro = lane & 15;
  const int xr7 = (fro & 7) << 4;                          // bytes
  const int c0  = ((((lane >> 4) << 4))      ^ xr7) >> 1;  // shorts
  const int c1  = ((64 + ((lane >> 4) << 4)) ^ xr7) >> 1;

  QKV_STAGE(0, lA0, lB0);
  __syncthreads();

  for (int kt = 0; kt < D_MODEL/64; ++kt) {
    const int cur = kt & 1;
    if (kt + 1 < D_MODEL/64)
      QKV_STAGE(kt + 1, cur ? lA0 : lA1, cur ? lB0 : lB1);
    const short* LA = cur ? lA1 : lA0;
    const short* LB = cur ? lB1 : lB0;
    #pragma unroll
    for (int ks2 = 0; ks2 < 2; ++ks2) {
      const int cc = ks2 ? c1 : c0;
      bf16x8 af[4], bfv[4];
      #pragma unroll
      for (int i = 0; i < 4; ++i)
        af[i] = *(const bf16x8*)&LA[(wr*64 + i*16 + fro)*64 + cc];
      #pragma unroll
      for (int j = 0; j < 4; ++j)
        bfv[j] = *(const bf16x8*)&LB[(wc*64 + j*16 + fro)*64 + cc];
      #pragma unroll
      for (int i = 0; i < 4; ++i)
        #pragma unroll
        for (int j = 0; j < 4; ++j)
          acc[i][j] = __builtin_amdgcn_mfma_f32_16x16x32_bf16(af[i], bfv[j], acc[i][j], 0, 0, 0);
    }
    __syncthreads();
  }
#undef QKV_STAGE

  if (z < 2) {
    const float sc = (z == 0) ? 0.125f*1.44269504f : 1.0f;
    short* out = (z == 0) ? qp : kp;
    #pragma unroll
    for (int i = 0; i < 4; ++i) {
      #pragma unroll
      for (int r = 0; r < 4; ++r) {
        const int m = bm*128 + wr*64 + i*16 + (lane>>4)*4 + r;
        const int b = m >> 11, s = m & (SEQ-1);
        #pragma unroll
        for (int j = 0; j < 4; ++j) {
          const int n = bn*128 + wc*64 + j*16 + fro;
          const int h = n >> 6, dh = n & 63;
          float v = (acc[i][j][r] + bias[n]) * sc;
          out[((size_t)(b*HEADS + h)*SEQ + s)*HDIM + dh] = (short)f2b(v);
        }
      }
    }
  } else {
    #pragma unroll
    for (int i = 0; i < 4; ++i) {
      #pragma unroll
      for (int r = 0; r < 4; ++r) {
        const int ml = wr*64 + i*16 + (lane>>4)*4 + r;
        #pragma unroll
        for (int j = 0; j < 4; ++j) {
          const int nl = wc*64 + j*16 + fro;
          lT[nl*129 + ml] = (short)f2b(acc[i][j][r] + bias[bn*128 + nl]);
        }
      }
    }
    __syncthreads();
    const int nl = tid >> 1, mh = (tid & 1) * 64;
    const int n = bn*128 + nl, h = n >> 6, dh = n & 63;
    const int b  = (bm*128) >> 11;
    const int s0 = (bm*128) & (SEQ-1);
    const size_t base = ((size_t)(b*HEADS + h)*HDIM + dh)*SEQ + s0 + mh;
    #pragma unroll
    for (int v8 = 0; v8 < 8; ++v8) {
      bf16x8 vv;
      #pragma unroll
      for (int e = 0; e < 8; ++e) vv[e] = lT[nl*129 + mh + v8*8 + e];
      *(bf16x8*)&vp[base + v8*8] = vv;
    }
  }
}

// ---- output projection, BK=64 + swizzle + double-buffer, f32 out ----
// (round-9 known-good)
__global__ __launch_bounds__(256)
void gemm_out(const short* __restrict__ A, const short* __restrict__ W,
              const float* __restrict__ bias, float* __restrict__ out)
{
  __shared__ __align__(16) char smemc[65536];
  short* const lA0 = (short*)smemc;
  short* const lA1 = (short*)(smemc + 16384);
  short* const lB0 = (short*)(smemc + 32768);
  short* const lB1 = (short*)(smemc + 49152);

  const int tid  = threadIdx.x;
  const int wid  = tid >> 6;
  const int lane = tid & 63;
  const int bm = blockIdx.x, bn = blockIdx.y;
  const int wr = wid >> 1, wc = wid & 1;

  f32x4 acc[4][4] = {};
  const int srow = tid >> 3;
  const int cswz = (((tid & 7) * 16) ^ ((srow & 7) << 4)) >> 1;
  const short* gA = A + (size_t)(bm*128 + srow)*D_MODEL + cswz;
  const short* gB = W + (size_t)(bn*128 + srow)*D_MODEL + cswz;

#define OUT_STAGE(kt, bA, bB) do { \
    const int ko_ = (kt)*64; \
    GLD16(gA + ko_,              (bA) + (     wid*8)*64); \
    GLD16(gA + 32*D_MODEL + ko_, (bA) + (32 + wid*8)*64); \
    GLD16(gA + 64*D_MODEL + ko_, (bA) + (64 + wid*8)*64); \
    GLD16(gA + 96*D_MODEL + ko_, (bA) + (96 + wid*8)*64); \
    GLD16(gB + ko_,              (bB) + (     wid*8)*64); \
    GLD16(gB + 32*D_MODEL + ko_, (bB) + (32 + wid*8)*64); \
    GLD16(gB + 64*D_MODEL + ko_, (bB) + (64 + wid*8)*64); \
    GLD16(gB + 96*D_MODEL + ko_, (bB) + (96 + wid*8)*64); \
  } while (0)

  const int fro = lane & 15;
  const int xr7 = (fro & 7) << 4;
  const int c0  = ((((lane >> 4) << 4))      ^ xr7) >> 1;
  const int c1  = ((64 + ((lane >> 4) << 4)) ^ xr7) >> 1;

  OUT_STAGE(0, lA0, lB0);
  __syncthreads();

  for (int kt = 0; kt < D_MODEL/64; ++kt) {
    const int cur = kt & 1;
    if (kt + 1 < D_MODEL/64)
      OUT_STAGE(kt + 1, cur ? lA0 : lA1, cur ? lB0 : lB1);
    const short* LA = cur ? lA1 : lA0;
    const short* LB = cur ? lB1 : lB0;
    #pragma unroll
    for (int ks2 = 0; ks2 < 2; ++ks2) {
      const int cc = ks2 ? c1 : c0;
      bf16x8 af[4], bfv[4];
      #pragma unroll
      for (int i = 0; i < 4; ++i)
        af[i] = *(const bf16x8*)&LA[(wr*64 + i*16 + fro)*64 + cc];
      #pragma unroll
      for (int j = 0; j < 4; ++j)
        bfv[j] = *(const bf16x8*)&LB[(wc*64 + j*16 + fro)*64 + cc];
      #pragma unroll
      for (int i = 0; i < 4; ++i)
        #pragma unroll
        for (int j = 0; j < 4; ++j)
          acc[i][j] = __builtin_amdgcn_mfma_f32_16x16x32_bf16(af[i], bfv[j], acc[i][j], 0, 0, 0);
    }
    __syncthreads();
  }
#undef OUT_STAGE

  #pragma unroll
  for (int i = 0; i < 4; ++i) {
    #pragma unroll
    for (int r = 0; r < 4; ++r) {
      const int m = bm*128 + wr*64 + i*16 + (lane>>4)*4 + r;
      #pragma unroll
      for (int j = 0; j < 4; ++j) {
        const int n = bn*128 + wc*64 + j*16 + fro;
        out[(size_t)m*D_MODEL + n] = acc[i][j][r] + bias[n];
      }
    }
  }
}

// ---- flash attention v2: 4 waves, 2-way KV split, 2 q-tiles per wave ----
// half = wid>>1 selects KV range; sq = wid&1 selects 64-q group; each wave
// computes TWO 32-q tiles against the SAME K/V fragments -> per-CU LDS
// ds_read count halves vs the 8-wave version. Unnormalized softmax
// (exp2 absolute), additive cross-half combine at block end.
__global__ __launch_bounds__(256)
void attn(const short* __restrict__ qws, const short* __restrict__ kws,
          const short* __restrict__ vws, short* __restrict__ ctx)
{
  __shared__ __align__(16) short lK[2][2][64*64];   // [stream][dbuf] 32 KB
  __shared__ __align__(16) short lV[2][2][64*64];   // 32 KB

  const int tid = threadIdx.x, wid = tid >> 6, lane = tid & 63;
  const int half = wid >> 1, sq = wid & 1;
  const int bid = blockIdx.x;
  const int wg = (bid & 7) * 64 + (bid >> 3);   // XCD swizzle, bijective
  const int qt = wg & 15, bh = wg >> 4;
  const size_t hb = (size_t)bh * SEQ * HDIM;

  const int lane31 = lane & 31, hi = lane >> 5;
  const int grp = lane >> 3, gran = lane & 7;
  const int cswz = ((gran * 16) ^ (grp << 4)) >> 1;   // shorts

  const short* gK = kws + hb;
  const short* gV = vws + hb;   // [dh][s] for this bh

  // 2 waves per stream; each wave covers rows c*16 + sq*8 + grp (c=0..3)
#define STAGEKV(t, bb) do { \
    _Pragma("unroll") \
    for (int c_ = 0; c_ < 4; ++c_) { \
      GLD16(gK + (size_t)((t)*64 + c_*16 + sq*8 + grp)*HDIM + cswz, \
            &lK[half][bb][(c_*16 + sq*8)*64]); \
      GLD16(gV + (size_t)(c_*16 + sq*8 + grp)*SEQ + (t)*64 + cswz, \
            &lV[half][bb][(c_*16 + sq*8)*64]); \
    } } while (0)

  const int kt0 = half * 16;
  STAGEKV(kt0, 0);

  // Q fragments for two q-tiles: q0 rows, q1 = q0+32
  const int q0 = qt*128 + sq*64 + lane31;
  const short* gq0 = qws + hb + (size_t)q0*HDIM + hi*8;
  bf16x8 qa[4], qb[4];
  #pragma unroll
  for (int ks = 0; ks < 4; ++ks) {
    qa[ks] = *(const bf16x8*)(gq0 + ks*16);
    qb[ks] = *(const bf16x8*)(gq0 + 32*HDIM + ks*16);
  }

  f32x16 oa0 = {}, oa1 = {};    // tile0: dh 0..31 / 32..63, col q0
  f32x16 ob0 = {}, ob1 = {};    // tile1: col q1
  float la = 0.f, lb = 0.f;
  const int swz = (lane31 & 7) << 4;

  __syncthreads();   // drains STAGE(kt0)

  for (int k2 = 0; k2 < 16; ++k2) {
    const short* Kc = &lK[half][k2 & 1][0];
    const short* Vc = &lV[half][k2 & 1][0];
    if (k2 + 1 < 16) STAGEKV(kt0 + k2 + 1, (k2 + 1) & 1);

    #pragma unroll
    for (int kb = 0; kb < 2; ++kb) {
      // S^T = K Q^T over d=64, both q-tiles share kf (4 LDS reads, 8 mfma)
      f32x16 s0 = {}, s1 = {};
      __builtin_amdgcn_s_setprio(1);
      #pragma unroll
      for (int ks = 0; ks < 4; ++ks) {
        bf16x8 kf = *(const bf16x8*)&Kc[(kb*32 + lane31)*64 + (((ks*32 + hi*16) ^ swz) >> 1)];
        s0 = __builtin_amdgcn_mfma_f32_32x32x16_bf16(kf, qa[ks], s0, 0, 0, 0);
        s1 = __builtin_amdgcn_mfma_f32_32x32x16_bf16(kf, qb[ks], s1, 0, 0, 0);
      }
      __builtin_amdgcn_s_setprio(0);

      // unnormalized softmax, tile0
      float p[16]; float rs = 0.f;
      #pragma unroll
      for (int r = 0; r < 16; ++r) { p[r] = EXP2(s0[r]); rs += p[r]; }
      la += rs;
      unsigned w0 = cvtpk(p[0],  p[1]),  w1 = cvtpk(p[2],  p[3]);
      unsigned w2 = cvtpk(p[4],  p[5]),  w3 = cvtpk(p[6],  p[7]);
      unsigned w4 = cvtpk(p[8],  p[9]),  w5 = cvtpk(p[10], p[11]);
      unsigned w6 = cvtpk(p[12], p[13]), w7 = cvtpk(p[14], p[15]);
      unsigned y0 = hi ? w0 : w2, y1 = hi ? w1 : w3;
      unsigned y2 = hi ? w4 : w6, y3 = hi ? w5 : w7;
      unsigned z0 = (unsigned)__shfl_xor((int)y0, 32);
      unsigned z1 = (unsigned)__shfl_xor((int)y1, 32);
      unsigned z2 = (unsigned)__shfl_xor((int)y2, 32);
      unsigned z3 = (unsigned)__shfl_xor((int)y3, 32);
      u32x4 pw0 = { hi ? z0 : w0, hi ? z1 : w1, hi ? w2 : z0, hi ? w3 : z1 };
      u32x4 pw1 = { hi ? z2 : w4, hi ? z3 : w5, hi ? w6 : z2, hi ? w7 : z3 };
      bf16x8 paA0 = __builtin_bit_cast(bf16x8, pw0);
      bf16x8 paA1 = __builtin_bit_cast(bf16x8, pw1);

      // tile1
      #pragma unroll
      for (int r = 0; r < 16; ++r) p[r] = EXP2(s1[r]);
      rs = 0.f;
      #pragma unroll
      for (int r = 0; r < 16; ++r) rs += p[r];
      lb += rs;
      w0 = cvtpk(p[0],  p[1]);  w1 = cvtpk(p[2],  p[3]);
      w2 = cvtpk(p[4],  p[5]);  w3 = cvtpk(p[6],  p[7]);
      w4 = cvtpk(p[8],  p[9]);  w5 = cvtpk(p[10], p[11]);
      w6 = cvtpk(p[12], p[13]); w7 = cvtpk(p[14], p[15]);
      y0 = hi ? w0 : w2; y1 = hi ? w1 : w3;
      y2 = hi ? w4 : w6; y3 = hi ? w5 : w7;
      z0 = (unsigned)__shfl_xor((int)y0, 32);
      z1 = (unsigned)__shfl_xor((int)y1, 32);
      z2 = (unsigned)__shfl_xor((int)y2, 32);
      z3 = (unsigned)__shfl_xor((int)y3, 32);
      u32x4 pw2 = { hi ? z0 : w0, hi ? z1 : w1, hi ? w2 : z0, hi ? w3 : z1 };
      u32x4 pw3 = { hi ? z2 : w4, hi ? z3 : w5, hi ? w6 : z2, hi ? w7 : z3 };
      bf16x8 paB0 = __builtin_bit_cast(bf16x8, pw2);
      bf16x8 paB1 = __builtin_bit_cast(bf16x8, pw3);

      // O^T += V^T P^T: vf shared by both tiles (4 LDS reads, 8 mfma)
      __builtin_amdgcn_s_setprio(1);
      #pragma unroll
      for (int ksl = 0; ksl < 2; ++ksl) {
        const int vcol = ((kb*64 + ksl*32 + hi*16) ^ swz) >> 1;
        bf16x8 pavA = ksl ? paA1 : paA0;
        bf16x8 pavB = ksl ? paB1 : paB0;
        bf16x8 vf0 = *(const bf16x8*)&Vc[lane31*64 + vcol];
        bf16x8 vf1 = *(const bf16x8*)&Vc[(32 + lane31)*64 + vcol];
        oa0 = __builtin_amdgcn_mfma_f32_32x32x16_bf16(vf0, pavA, oa0, 0, 0, 0);
        oa1 = __builtin_amdgcn_mfma_f32_32x32x16_bf16(vf1, pavA, oa1, 0, 0, 0);
        ob0 = __builtin_amdgcn_mfma_f32_32x32x16_bf16(vf0, pavB, ob0, 0, 0, 0);
        ob1 = __builtin_amdgcn_mfma_f32_32x32x16_bf16(vf1, pavB, ob1, 0, 0, 0);
      }
      __builtin_amdgcn_s_setprio(0);
    }
    __syncthreads();
  }

  la += __shfl_xor(la, 32);
  lb += __shfl_xor(lb, 32);

  // cross-half combine (barrier-separated from last K/V reads):
  // half==1 deposits 4 acc tiles + 2 l's; half==0 adds, normalizes, writes.
  float* xo = (float*)&lK[0][0][0];   // (2 sq x 2 tile) x 64 dh x 32 q = 32 KB
  float* xl = (float*)&lV[0][0][0];
  if (half == 1) {
    const int bA = (sq*2 + 0)*2048, bB = (sq*2 + 1)*2048;
    #pragma unroll
    for (int g = 0; g < 4; ++g) {
      #pragma unroll
      for (int e = 0; e < 4; ++e) {
        const int dh = g*8 + hi*4 + e;
        xo[bA + dh*32 + lane31]        = oa0[g*4 + e];
        xo[bA + (32 + dh)*32 + lane31] = oa1[g*4 + e];
        xo[bB + dh*32 + lane31]        = ob0[g*4 + e];
        xo[bB + (32 + dh)*32 + lane31] = ob1[g*4 + e];
      }
    }
    if (hi == 0) {
      xl[(sq*2 + 0)*32 + lane31] = la;
      xl[(sq*2 + 1)*32 + lane31] = lb;
    }
  }
  __syncthreads();
  if (half == 0) {
    const int b_ = bh >> 4, h_ = bh & (HEADS-1);
    const float invA = 1.0f / (la + xl[(sq*2 + 0)*32 + lane31]);
    const float invB = 1.0f / (lb + xl[(sq*2 + 1)*32 + lane31]);
    const int bA = (sq*2 + 0)*2048, bB = (sq*2 + 1)*2048;
    const size_t baseA = ((size_t)(b_*SEQ) + q0)*D_MODEL + h_*HDIM;
    const size_t baseB = baseA + (size_t)32*D_MODEL;
    #pragma unroll
    for (int g = 0; g < 4; ++g) {
      s16x4 a0, a1, b0v, b1v;
      #pragma unroll
      for (int e = 0; e < 4; ++e) {
        const int dh = g*8 + hi*4 + e;
        a0[e]  = (short)f2b((oa0[g*4+e] + xo[bA + dh*32 + lane31]) * invA);
        a1[e]  = (short)f2b((oa1[g*4+e] + xo[bA + (32+dh)*32 + lane31]) * invA);
        b0v[e] = (short)f2b((ob0[g*4+e] + xo[bB + dh*32 + lane31]) * invB);
        b1v[e] = (short)f2b((ob1[g*4+e] + xo[bB + (32+dh)*32 + lane31]) * invB);
      }
      *(s16x4*)&ctx[baseA +      g*8 + hi*4] = a0;
      *(s16x4*)&ctx[baseA + 32 + g*8 + hi*4] = a1;
      *(s16x4*)&ctx[baseB +      g*8 + hi*4] = b0v;
      *(s16x4*)&ctx[baseB + 32 + g*8 + hi*4] = b1v;
    }
  }
#undef STAGEKV
}

extern "C" void kernel_launch(void* const* d_in, const int* in_sizes, int n_in,
                              void* d_out, int out_size, void* d_ws, size_t ws_size,
                              hipStream_t stream)
{
  const float* Q  = (const float*)d_in[0];
  const float* K  = (const float*)d_in[1];
  const float* V  = (const float*)d_in[2];
  const float* Wq = (const float*)d_in[3];
  const float* bq = (const float*)d_in[4];
  const float* Wk = (const float*)d_in[5];
  const float* bk = (const float*)d_in[6];
  const float* Wv = (const float*)d_in[7];
  const float* bv = (const float*)d_in[8];
  const float* Wo = (const float*)d_in[9];
  const float* bo = (const float*)d_in[10];

  char* ws = (char*)d_ws;
  const size_t MB = 1024*1024;
  short* Qb  = (short*)(ws +  0*MB);
  short* Kb  = (short*)(ws +  8*MB);
  short* Vb  = (short*)(ws + 16*MB);
  short* Wqb = (short*)(ws + 24*MB);
  short* Wkb = (short*)(ws + 26*MB);
  short* Wvb = (short*)(ws + 28*MB);
  short* Wob = (short*)(ws + 30*MB);
  short* qp  = (short*)(ws + 32*MB);
  short* kp  = (short*)(ws + 40*MB);
  short* vp  = (short*)(ws + 48*MB);
  short* cx  = (short*)(ws + 56*MB);

  cast_all<<<8192, 256, 0, stream>>>(Q, K, V, Wq, Wk, Wv, Wo, ws);
  gemm_qkv<<<dim3(MROWS/128, D_MODEL/128, 3), 256, 0, stream>>>(
      Qb, Kb, Vb, Wqb, Wkb, Wvb, bq, bk, bv, qp, kp, vp);
  attn<<<512, 256, 0, stream>>>(qp, kp, vp, cx);
  gemm_out<<<dim3(MROWS/128, D_MODEL/128), 256, 0, stream>>>(cx, Wob, bo, (float*)d_out);
}

// Round 12
// 119.400 us; speedup vs baseline: 1.0670x; 1.0670x over previous
//
#include <hip/hip_runtime.h>
#include <hip/hip_bf16.h>

#define D_MODEL 1024
#define HEADS 16
#define HDIM 64
#define BATCH 2
#define SEQ 2048
#define MROWS (BATCH*SEQ)   // 4096

typedef __attribute__((ext_vector_type(8))) short bf16x8;
typedef __attribute__((ext_vector_type(4))) float f32x4;
typedef __attribute__((ext_vector_type(16))) float f32x16;
typedef __attribute__((ext_vector_type(4))) float float4v;
typedef __attribute__((ext_vector_type(4))) unsigned u32x4;
typedef __attribute__((ext_vector_type(4))) short s16x4;

typedef const __attribute__((address_space(1))) void gconst_t;
typedef __attribute__((address_space(3))) void lds_t;
#define GLD16(g, l) __builtin_amdgcn_global_load_lds((gconst_t*)(g), (lds_t*)(l), 16, 0, 0)

#if __has_builtin(__builtin_amdgcn_exp2f)
#define EXP2(x) __builtin_amdgcn_exp2f(x)   // raw v_exp_f32, intrinsic (not asm)
#else
#define EXP2(x) __builtin_exp2f(x)
#endif

__device__ __forceinline__ unsigned short f2b(float f) {
  unsigned u = __builtin_bit_cast(unsigned, f);
  u += 0x7fffu + ((u >> 16) & 1u);
  return (unsigned short)(u >> 16);
}

__device__ __forceinline__ unsigned cvtpk(float lo, float hi) {
  unsigned r;
  asm volatile("v_cvt_pk_bf16_f32 %0, %1, %2" : "=v"(r) : "v"(lo), "v"(hi));
  return r;
}

__global__ __launch_bounds__(256)
void cast_all(const float* __restrict__ Q, const float* __restrict__ K,
              const float* __restrict__ V, const float* __restrict__ Wq,
              const float* __restrict__ Wk, const float* __restrict__ Wv,
              const float* __restrict__ Wo, char* __restrict__ ws)
{
  const size_t MB = 1024*1024;
  int b = blockIdx.x;
  const float* src; short* dst; int rb;
  if (b < 6144) {
    int t = b >> 11; rb = b & 2047;
    src = (t == 0) ? Q : (t == 1) ? K : V;
    dst = (short*)(ws + (size_t)t*8*MB);
  } else {
    int t = (b - 6144) >> 9; rb = (b - 6144) & 511;
    src = (t == 0) ? Wq : (t == 1) ? Wk : (t == 2) ? Wv : Wo;
    dst = (short*)(ws + (24 + 2*(size_t)t)*MB);
  }
  int i = rb*256 + threadIdx.x;
  const float4v* s = (const float4v*)src;
  float4v a = s[2*(size_t)i], c = s[2*(size_t)i + 1];
  bf16x8 o;
  o[0] = (short)f2b(a[0]); o[1] = (short)f2b(a[1]);
  o[2] = (short)f2b(a[2]); o[3] = (short)f2b(a[3]);
  o[4] = (short)f2b(c[0]); o[5] = (short)f2b(c[1]);
  o[6] = (short)f2b(c[2]); o[7] = (short)f2b(c[3]);
  *(bf16x8*)(dst + 8*(size_t)i) = o;
}

// ---- merged Q/K/V projection GEMM, BK=64, XOR-swizzled, DOUBLE-BUFFERED ----
// (round-9 known-good) z=0: Q -> qp scaled by 0.125*log2e; z=1: K; z=2: V^T.
__global__ __launch_bounds__(256)
void gemm_qkv(const short* __restrict__ Qb, const short* __restrict__ Kb,
              const short* __restrict__ Vb, const short* __restrict__ Wqb,
              const short* __restrict__ Wkb, const short* __restrict__ Wvb,
              const float* __restrict__ bq, const float* __restrict__ bk,
              const float* __restrict__ bv, short* __restrict__ qp,
              short* __restrict__ kp, short* __restrict__ vp)
{
  __shared__ __align__(16) char smemc[65536];
  short* const lA0 = (short*)smemc;                 // buf0 A (16 KB)
  short* const lA1 = (short*)(smemc + 16384);       // buf1 A
  short* const lB0 = (short*)(smemc + 32768);       // buf0 B
  short* const lB1 = (short*)(smemc + 49152);       // buf1 B
  short* const lT  = (short*)smemc;                 // epilogue reuse (33 KB)

  const int z = blockIdx.z;
  const short* A = (z == 0) ? Qb : (z == 1) ? Kb : Vb;
  const short* W = (z == 0) ? Wqb : (z == 1) ? Wkb : Wvb;
  const float* bias = (z == 0) ? bq : (z == 1) ? bk : bv;

  const int tid  = threadIdx.x;
  const int wid  = tid >> 6;
  const int lane = tid & 63;
  const int bm = blockIdx.x, bn = blockIdx.y;
  const int wr = wid >> 1, wc = wid & 1;

  f32x4 acc[4][4] = {};

  const int srow = tid >> 3;
  const int cswz = (((tid & 7) * 16) ^ ((srow & 7) << 4)) >> 1;
  const short* gA = A + (size_t)(bm*128 + srow)*D_MODEL + cswz;
  const short* gB = W + (size_t)(bn*128 + srow)*D_MODEL + cswz;

#define QKV_STAGE(kt, bA, bB) do { \
    const int ko_ = (kt)*64; \
    GLD16(gA + ko_,              (bA) + (     wid*8)*64); \
    GLD16(gA + 32*D_MODEL + ko_, (bA) + (32 + wid*8)*64); \
    GLD16(gA + 64*D_MODEL + ko_, (bA) + (64 + wid*8)*64); \
    GLD16(gA + 96*D_MODEL + ko_, (bA) + (96 + wid*8)*64); \
    GLD16(gB + ko_,              (bB) + (     wid*8)*64); \
    GLD16(gB + 32*D_MODEL + ko_, (bB) + (32 + wid*8)*64); \
    GLD16(gB + 64*D_MODEL + ko_, (bB) + (64 + wid*8)*64); \
    GLD16(gB + 96*D_MODEL + ko_, (bB) + (96 + wid*8)*64); \
  } while (0)

  const int fro = lane & 15;
  const int xr7 = (fro & 7) << 4;                          // bytes
  const int c0  = ((((lane >> 4) << 4))      ^ xr7) >> 1;  // shorts
  const int c1  = ((64 + ((lane >> 4) << 4)) ^ xr7) >> 1;

  QKV_STAGE(0, lA0, lB0);
  __syncthreads();

  for (int kt = 0; kt < D_MODEL/64; ++kt) {
    const int cur = kt & 1;
    if (kt + 1 < D_MODEL/64)
      QKV_STAGE(kt + 1, cur ? lA0 : lA1, cur ? lB0 : lB1);
    const short* LA = cur ? lA1 : lA0;
    const short* LB = cur ? lB1 : lB0;
    #pragma unroll
    for (int ks2 = 0; ks2 < 2; ++ks2) {
      const int cc = ks2 ? c1 : c0;
      bf16x8 af[4], bfv[4];
      #pragma unroll
      for (int i = 0; i < 4; ++i)
        af[i] = *(const bf16x8*)&LA[(wr*64 + i*16 + fro)*64 + cc];
      #pragma unroll
      for (int j = 0; j < 4; ++j)
        bfv[j] = *(const bf16x8*)&LB[(wc*64 + j*16 + fro)*64 + cc];
      #pragma unroll
      for (int i = 0; i < 4; ++i)
        #pragma unroll
        for (int j = 0; j < 4; ++j)
          acc[i][j] = __builtin_amdgcn_mfma_f32_16x16x32_bf16(af[i], bfv[j], acc[i][j], 0, 0, 0);
    }
    __syncthreads();
  }
#undef QKV_STAGE

  if (z < 2) {
    const float sc = (z == 0) ? 0.125f*1.44269504f : 1.0f;
    short* out = (z == 0) ? qp : kp;
    #pragma unroll
    for (int i = 0; i < 4; ++i) {
      #pragma unroll
      for (int r = 0; r < 4; ++r) {
        const int m = bm*128 + wr*64 + i*16 + (lane>>4)*4 + r;
        const int b = m >> 11, s = m & (SEQ-1);
        #pragma unroll
        for (int j = 0; j < 4; ++j) {
          const int n = bn*128 + wc*64 + j*16 + fro;
          const int h = n >> 6, dh = n & 63;
          float v = (acc[i][j][r] + bias[n]) * sc;
          out[((size_t)(b*HEADS + h)*SEQ + s)*HDIM + dh] = (short)f2b(v);
        }
      }
    }
  } else {
    #pragma unroll
    for (int i = 0; i < 4; ++i) {
      #pragma unroll
      for (int r = 0; r < 4; ++r) {
        const int ml = wr*64 + i*16 + (lane>>4)*4 + r;
        #pragma unroll
        for (int j = 0; j < 4; ++j) {
          const int nl = wc*64 + j*16 + fro;
          lT[nl*129 + ml] = (short)f2b(acc[i][j][r] + bias[bn*128 + nl]);
        }
      }
    }
    __syncthreads();
    const int nl = tid >> 1, mh = (tid & 1) * 64;
    const int n = bn*128 + nl, h = n >> 6, dh = n & 63;
    const int b  = (bm*128) >> 11;
    const int s0 = (bm*128) & (SEQ-1);
    const size_t base = ((size_t)(b*HEADS + h)*HDIM + dh)*SEQ + s0 + mh;
    #pragma unroll
    for (int v8 = 0; v8 < 8; ++v8) {
      bf16x8 vv;
      #pragma unroll
      for (int e = 0; e < 8; ++e) vv[e] = lT[nl*129 + mh + v8*8 + e];
      *(bf16x8*)&vp[base + v8*8] = vv;
    }
  }
}

// ---- output projection, BK=64 + swizzle + double-buffer, f32 out ----
// (round-9 known-good)
__global__ __launch_bounds__(256)
void gemm_out(const short* __restrict__ A, const short* __restrict__ W,
              const float* __restrict__ bias, float* __restrict__ out)
{
  __shared__ __align__(16) char smemc[65536];
  short* const lA0 = (short*)smemc;
  short* const lA1 = (short*)(smemc + 16384);
  short* const lB0 = (short*)(smemc + 32768);
  short* const lB1 = (short*)(smemc + 49152);

  const int tid  = threadIdx.x;
  const int wid  = tid >> 6;
  const int lane = tid & 63;
  const int bm = blockIdx.x, bn = blockIdx.y;
  const int wr = wid >> 1, wc = wid & 1;

  f32x4 acc[4][4] = {};
  const int srow = tid >> 3;
  const int cswz = (((tid & 7) * 16) ^ ((srow & 7) << 4)) >> 1;
  const short* gA = A + (size_t)(bm*128 + srow)*D_MODEL + cswz;
  const short* gB = W + (size_t)(bn*128 + srow)*D_MODEL + cswz;

#define OUT_STAGE(kt, bA, bB) do { \
    const int ko_ = (kt)*64; \
    GLD16(gA + ko_,              (bA) + (     wid*8)*64); \
    GLD16(gA + 32*D_MODEL + ko_, (bA) + (32 + wid*8)*64); \
    GLD16(gA + 64*D_MODEL + ko_, (bA) + (64 + wid*8)*64); \
    GLD16(gA + 96*D_MODEL + ko_, (bA) + (96 + wid*8)*64); \
    GLD16(gB + ko_,              (bB) + (     wid*8)*64); \
    GLD16(gB + 32*D_MODEL + ko_, (bB) + (32 + wid*8)*64); \
    GLD16(gB + 64*D_MODEL + ko_, (bB) + (64 + wid*8)*64); \
    GLD16(gB + 96*D_MODEL + ko_, (bB) + (96 + wid*8)*64); \
  } while (0)

  const int fro = lane & 15;
  const int xr7 = (fro & 7) << 4;
  const int c0  = ((((lane >> 4) << 4))      ^ xr7) >> 1;
  const int c1  = ((64 + ((lane >> 4) << 4)) ^ xr7) >> 1;

  OUT_STAGE(0, lA0, lB0);
  __syncthreads();

  for (int kt = 0; kt < D_MODEL/64; ++kt) {
    const int cur = kt & 1;
    if (kt + 1 < D_MODEL/64)
      OUT_STAGE(kt + 1, cur ? lA0 : lA1, cur ? lB0 : lB1);
    const short* LA = cur ? lA1 : lA0;
    const short* LB = cur ? lB1 : lB0;
    #pragma unroll
    for (int ks2 = 0; ks2 < 2; ++ks2) {
      const int cc = ks2 ? c1 : c0;
      bf16x8 af[4], bfv[4];
      #pragma unroll
      for (int i = 0; i < 4; ++i)
        af[i] = *(const bf16x8*)&LA[(wr*64 + i*16 + fro)*64 + cc];
      #pragma unroll
      for (int j = 0; j < 4; ++j)
        bfv[j] = *(const bf16x8*)&LB[(wc*64 + j*16 + fro)*64 + cc];
      #pragma unroll
      for (int i = 0; i < 4; ++i)
        #pragma unroll
        for (int j = 0; j < 4; ++j)
          acc[i][j] = __builtin_amdgcn_mfma_f32_16x16x32_bf16(af[i], bfv[j], acc[i][j], 0, 0, 0);
    }
    __syncthreads();
  }
#undef OUT_STAGE

  #pragma unroll
  for (int i = 0; i < 4; ++i) {
    #pragma unroll
    for (int r = 0; r < 4; ++r) {
      const int m = bm*128 + wr*64 + i*16 + (lane>>4)*4 + r;
      #pragma unroll
      for (int j = 0; j < 4; ++j) {
        const int n = bn*128 + wc*64 + j*16 + fro;
        out[(size_t)m*D_MODEL + n] = acc[i][j][r] + bias[n];
      }
    }
  }
}

// ---- flash attention, 8 waves, 2-way KV split inside the block ----
// (round-9 known-good structure; rs sum restructured as pairwise tree)
__global__ __launch_bounds__(512)
void attn(const short* __restrict__ qws, const short* __restrict__ kws,
          const short* __restrict__ vws, short* __restrict__ ctx)
{
  __shared__ __align__(16) short lK[2][2][64*64];   // [stream][dbuf]
  __shared__ __align__(16) short lV[2][2][64*64];

  const int tid = threadIdx.x, wid = tid >> 6, lane = tid & 63;
  const int sw = wid & 3, half = wid >> 2;
  const int bid = blockIdx.x;
  const int wg = (bid & 7) * 64 + (bid >> 3);   // XCD swizzle, bijective
  const int qt = wg & 15, bh = wg >> 4;
  const size_t hb = (size_t)bh * SEQ * HDIM;

  const int lane31 = lane & 31, hi = lane >> 5;
  const int tidl = sw*64 + lane;                               // 0..255/stream
  const int tr0  = tidl >> 3;                                  // 0..31
  const int cswz = (((tidl & 7) * 16) ^ ((tr0 & 7) << 4)) >> 1;

  const short* gK = kws + hb;
  const short* gV = vws + hb;   // [dh][s] for this bh

#define STAGEKV(t, bb) do { \
    GLD16(gK + (size_t)((t)*64 + tr0)*HDIM + cswz,      &lK[half][bb][(sw*8)*64]); \
    GLD16(gK + (size_t)((t)*64 + 32 + tr0)*HDIM + cswz, &lK[half][bb][(32+sw*8)*64]); \
    GLD16(gV + (size_t)tr0*SEQ + (t)*64 + cswz,         &lV[half][bb][(sw*8)*64]); \
    GLD16(gV + (size_t)(32+tr0)*SEQ + (t)*64 + cswz,    &lV[half][bb][(32+sw*8)*64]); \
  } while (0)

  const int kt0 = half * 16;
  STAGEKV(kt0, 0);

  // Q fragment: Q[q=lane31][d = ks*16 + hi*8 + j]
  const int q = qt*128 + sw*32 + lane31;
  const short* gq = qws + hb + (size_t)q*HDIM + hi*8;
  bf16x8 qf[4];
  #pragma unroll
  for (int ks = 0; ks < 4; ++ks) qf[ks] = *(const bf16x8*)(gq + ks*16);

  f32x16 o0 = {}, o1 = {};      // O^T tiles: dh 0..31 / 32..63, col q=lane31
  float lrow = 0.f;
  const int swz = (lane31 & 7) << 4;

  __syncthreads();   // drains STAGE(kt0)

  for (int k2 = 0; k2 < 16; ++k2) {
    const short* Kc = &lK[half][k2 & 1][0];
    const short* Vc = &lV[half][k2 & 1][0];
    if (k2 + 1 < 16) STAGEKV(kt0 + k2 + 1, (k2 + 1) & 1);

    #pragma unroll
    for (int kb = 0; kb < 2; ++kb) {
      // S^T = K Q^T over d=64 (4 mfma)
      f32x16 s = {};
      __builtin_amdgcn_s_setprio(1);
      #pragma unroll
      for (int ks = 0; ks < 4; ++ks) {
        bf16x8 kf = *(const bf16x8*)&Kc[(kb*32 + lane31)*64 + (((ks*32 + hi*16) ^ swz) >> 1)];
        s = __builtin_amdgcn_mfma_f32_32x32x16_bf16(kf, qf[ks], s, 0, 0, 0);
      }
      __builtin_amdgcn_s_setprio(0);

      // unnormalized: p = exp2(s) directly; pairwise-tree sum (dep chain 4)
      float p[16];
      #pragma unroll
      for (int r = 0; r < 16; ++r) p[r] = EXP2(s[r]);
      {
        float t0 = (p[0] + p[1]) + (p[2] + p[3]);
        float t1 = (p[4] + p[5]) + (p[6] + p[7]);
        float t2 = (p[8] + p[9]) + (p[10] + p[11]);
        float t3 = (p[12] + p[13]) + (p[14] + p[15]);
        lrow += (t0 + t1) + (t2 + t3);
      }

      // P -> bf16 B-fragments (4 cross-half shfls)
      unsigned w0 = cvtpk(p[0],  p[1]),  w1 = cvtpk(p[2],  p[3]);
      unsigned w2 = cvtpk(p[4],  p[5]),  w3 = cvtpk(p[6],  p[7]);
      unsigned w4 = cvtpk(p[8],  p[9]),  w5 = cvtpk(p[10], p[11]);
      unsigned w6 = cvtpk(p[12], p[13]), w7 = cvtpk(p[14], p[15]);
      unsigned y0 = hi ? w0 : w2, y1 = hi ? w1 : w3;
      unsigned y2 = hi ? w4 : w6, y3 = hi ? w5 : w7;
      unsigned z0 = (unsigned)__shfl_xor((int)y0, 32);
      unsigned z1 = (unsigned)__shfl_xor((int)y1, 32);
      unsigned z2 = (unsigned)__shfl_xor((int)y2, 32);
      unsigned z3 = (unsigned)__shfl_xor((int)y3, 32);
      u32x4 pw0 = { hi ? z0 : w0, hi ? z1 : w1, hi ? w2 : z0, hi ? w3 : z1 };
      u32x4 pw1 = { hi ? z2 : w4, hi ? z3 : w5, hi ? w6 : z2, hi ? w7 : z3 };
      bf16x8 pa0 = __builtin_bit_cast(bf16x8, pw0);
      bf16x8 pa1 = __builtin_bit_cast(bf16x8, pw1);

      // O^T += V^T P^T (4 mfma)
      __builtin_amdgcn_s_setprio(1);
      #pragma unroll
      for (int ksl = 0; ksl < 2; ++ksl) {
        const int vcol = ((kb*64 + ksl*32 + hi*16) ^ swz) >> 1;
        bf16x8 pav = ksl ? pa1 : pa0;
        bf16x8 vf0 = *(const bf16x8*)&Vc[lane31*64 + vcol];
        bf16x8 vf1 = *(const bf16x8*)&Vc[(32 + lane31)*64 + vcol];
        o0 = __builtin_amdgcn_mfma_f32_32x32x16_bf16(vf0, pav, o0, 0, 0, 0);
        o1 = __builtin_amdgcn_mfma_f32_32x32x16_bf16(vf1, pav, o1, 0, 0, 0);
      }
      __builtin_amdgcn_s_setprio(0);
    }
    __syncthreads();
  }

  lrow += __shfl_xor(lrow, 32);   // half-total over this wave's KV range

  // cross-half combine: waves 4-7 deposit o-tiles + l into LDS (barrier-
  // separated from last K/V reads), waves 0-3 add, normalize, write ctx.
  float* xo = (float*)&lK[0][0][0];   // 4 waves x 64dh x 32q f32 = 32 KB
  float* xl = (float*)&lV[0][0][0];
  if (half == 1) {
    #pragma unroll
    for (int g = 0; g < 4; ++g) {
      #pragma unroll
      for (int e = 0; e < 4; ++e) {
        const int dh = g*8 + hi*4 + e;
        xo[sw*2048 + dh*32 + lane31]        = o0[g*4 + e];
        xo[sw*2048 + (32 + dh)*32 + lane31] = o1[g*4 + e];
      }
    }
    if (hi == 0) xl[sw*32 + lane31] = lrow;
  }
  __syncthreads();
  if (half == 0) {
    const float inv = 1.0f / (lrow + xl[sw*32 + lane31]);
    const int b_ = bh >> 4, h_ = bh & (HEADS-1);
    const size_t base = ((size_t)(b_*SEQ) + q)*D_MODEL + h_*HDIM;
    #pragma unroll
    for (int g = 0; g < 4; ++g) {
      s16x4 pk0, pk1;
      #pragma unroll
      for (int e = 0; e < 4; ++e) {
        const int dh = g*8 + hi*4 + e;
        pk0[e] = (short)f2b((o0[g*4+e] + xo[sw*2048 + dh*32 + lane31]) * inv);
        pk1[e] = (short)f2b((o1[g*4+e] + xo[sw*2048 + (32+dh)*32 + lane31]) * inv);
      }
      *(s16x4*)&ctx[base +      g*8 + hi*4] = pk0;
      *(s16x4*)&ctx[base + 32 + g*8 + hi*4] = pk1;
    }
  }
#undef STAGEKV
}

extern "C" void kernel_launch(void* const* d_in, const int* in_sizes, int n_in,
                              void* d_out, int out_size, void* d_ws, size_t ws_size,
                              hipStream_t stream)
{
  const float* Q  = (const float*)d_in[0];
  const float* K  = (const float*)d_in[1];
  const float* V  = (const float*)d_in[2];
  const float* Wq = (const float*)d_in[3];
  const float* bq = (const float*)d_in[4];
  const float* Wk = (const float*)d_in[5];
  const float* bk = (const float*)d_in[6];
  const float* Wv = (const float*)d_in[7];
  const float* bv = (const float*)d_in[8];
  const float* Wo = (const float*)d_in[9];
  const float* bo = (const float*)d_in[10];

  char* ws = (char*)d_ws;
  const size_t MB = 1024*1024;
  short* Qb  = (short*)(ws +  0*MB);
  short* Kb  = (short*)(ws +  8*MB);
  short* Vb  = (short*)(ws + 16*MB);
  short* Wqb = (short*)(ws + 24*MB);
  short* Wkb = (short*)(ws + 26*MB);
  short* Wvb = (short*)(ws + 28*MB);
  short* Wob = (short*)(ws + 30*MB);
  short* qp  = (short*)(ws + 32*MB);
  short* kp  = (short*)(ws + 40*MB);
  short* vp  = (short*)(ws + 48*MB);
  short* cx  = (short*)(ws + 56*MB);

  cast_all<<<8192, 256, 0, stream>>>(Q, K, V, Wq, Wk, Wv, Wo, ws);
  gemm_qkv<<<dim3(MROWS/128, D_MODEL/128, 3), 256, 0, stream>>>(
      Qb, Kb, Vb, Wqb, Wkb, Wvb, bq, bk, bv, qp, kp, vp);
  attn<<<512, 512, 0, stream>>>(qp, kp, vp, cx);
  gemm_out<<<dim3(MROWS/128, D_MODEL/128), 256, 0, stream>>>(cx, Wob, bo, (float*)d_out);
}